// Round 4
// baseline (309.947 us; speedup 1.0000x reference)
//
#include <hip/hip_runtime.h>

typedef unsigned short u16;
typedef unsigned int   u32;
typedef unsigned char  u8;

using bf16x8 = __attribute__((ext_vector_type(8))) __bf16;
using f32x4  = __attribute__((ext_vector_type(4))) float;

__device__ __forceinline__ u16 f2bf(float f) {
    u32 u = __float_as_uint(f);
    return (u16)((u + 0x7FFFu + ((u >> 16) & 1u)) >> 16);
}

#define MFMA(a, b, c) __builtin_amdgcn_mfma_f32_16x16x32_bf16((a), (b), (c), 0, 0, 0)

// async global->LDS 16B: per-lane global source, wave-uniform LDS base + lane*16
__device__ __forceinline__ void gll16(const u16* g, u16* l) {
    __builtin_amdgcn_global_load_lds(
        (const __attribute__((address_space(1))) void*)g,
        (__attribute__((address_space(3))) void*)l, 16, 0, 0);
}

// ---------------------------------------------------------------------------
// Wt[n][k] = bf16(W[k][n]) for 4 weights in one launch. N = K = 1280.
// ---------------------------------------------------------------------------
__global__ __launch_bounds__(256) void wtrans_kernel(
    const float* __restrict__ W0, const float* __restrict__ W1,
    const float* __restrict__ W2, const float* __restrict__ W3,
    u16* __restrict__ T0, u16* __restrict__ T1,
    u16* __restrict__ T2, u16* __restrict__ T3) {
    const int N = 1280;
    const int z = blockIdx.z;
    const float* W = (z == 0) ? W0 : (z == 1) ? W1 : (z == 2) ? W2 : W3;
    u16* T = (z == 0) ? T0 : (z == 1) ? T1 : (z == 2) ? T2 : T3;
    __shared__ float t[32][33];
    const int bx = blockIdx.x * 32, by = blockIdx.y * 32;
    const int x = threadIdx.x, ty = threadIdx.y;
#pragma unroll
    for (int j = 0; j < 4; j++) {
        const int y = ty + j * 8;
        t[y][x] = W[(size_t)(by + y) * N + (bx + x)];
    }
    __syncthreads();
#pragma unroll
    for (int j = 0; j < 4; j++) {
        const int y = ty + j * 8;
        T[(size_t)(bx + y) * N + (by + x)] = f2bf(t[x][y]);
    }
}

// ---------------------------------------------------------------------------
// fp32 -> bf16 convert, 8 elems/thread
// ---------------------------------------------------------------------------
__global__ __launch_bounds__(256) void conv_kernel(const float* __restrict__ in,
                                                   u16* __restrict__ out, int n8) {
    const int i = blockIdx.x * 256 + threadIdx.x;
    if (i >= n8) return;
    const float4 a = ((const float4*)in)[i * 2];
    const float4 b = ((const float4*)in)[i * 2 + 1];
    union { uint4 u; u16 s[8]; } cv;
    cv.s[0] = f2bf(a.x); cv.s[1] = f2bf(a.y); cv.s[2] = f2bf(a.z); cv.s[3] = f2bf(a.w);
    cv.s[4] = f2bf(b.x); cv.s[5] = f2bf(b.y); cv.s[6] = f2bf(b.z); cv.s[7] = f2bf(b.w);
    ((uint4*)out)[i] = cv.u;
}

// ---------------------------------------------------------------------------
// C[M,N] = A[M,K] @ Bt[N,K]^T, bf16 in. m97-structure: global_load_lds into
// linear LDS, pre-swizzled source chunk (^= row&7), swizzled ds_read_b128,
// double-buffered, one vmcnt(0)+barrier per K-tile. BM=MI*32, BN=128.
// 256 thr, 4 waves each (MI*16)x64 out.
// EPI: fp32 out = acc + bias + resid. TRANSC: C[row= c][col= b*2048+s] stored
// to [(col>>11)*1280 + row][col&2047] (i.e. Vt[b][c][s], contiguous in s).
// ---------------------------------------------------------------------------
template <int MI, bool TRANSC, bool EPI>
__global__ __launch_bounds__(256) void gemm2_kernel(
    const u16* __restrict__ A, const u16* __restrict__ Bt, void* __restrict__ Cp,
    const float* __restrict__ bias, const float* __restrict__ resid,
    const int M, const int N, const int K) {
    __shared__ __align__(16) u16 Al[2][MI * 32 * 64];
    __shared__ __align__(16) u16 Bl[2][128 * 64];
    const int tid = threadIdx.x;
    const int lane = tid & 63, w = tid >> 6;
    const int wr = w >> 1, wc = w & 1;
    const int lr = lane & 15, lq = lane >> 4;
    const int m0 = blockIdx.y * (MI * 32), n0 = blockIdx.x * 128;

    const int f_r = tid >> 3;                       // row within 32-row pass
    const int srcch = (tid & 7) ^ ((tid >> 3) & 7); // swizzled source chunk
    const int ldst = (tid & 192) * 8;               // wave-uniform LDS u16 base

    const f32x4 fzero = {0.f, 0.f, 0.f, 0.f};
    f32x4 acc[MI][4];
#pragma unroll
    for (int i = 0; i < MI; i++)
#pragma unroll
        for (int j = 0; j < 4; j++) acc[i][j] = fzero;

    const int nkt = K >> 6;

#define STAGE(buf, kt)                                                          \
    {                                                                           \
        const int k0s = (kt) << 6;                                              \
        _Pragma("unroll")                                                       \
        for (int i = 0; i < MI; i++) {                                          \
            const int r = i * 32 + f_r;                                         \
            gll16(&A[(size_t)(m0 + r) * K + k0s + srcch * 8],                   \
                  &Al[buf][i * 2048 + ldst]);                                   \
        }                                                                       \
        _Pragma("unroll")                                                       \
        for (int i = 0; i < 4; i++) {                                           \
            const int r = i * 32 + f_r;                                         \
            gll16(&Bt[(size_t)(n0 + r) * K + k0s + srcch * 8],                  \
                  &Bl[buf][i * 2048 + ldst]);                                   \
        }                                                                       \
    }

    STAGE(0, 0);
    asm volatile("s_waitcnt vmcnt(0)" ::: "memory");
    __syncthreads();
    int cur = 0;
    for (int kt = 0; kt < nkt; kt++) {
        if (kt + 1 < nkt) STAGE(cur ^ 1, kt + 1);
#pragma unroll
        for (int ks = 0; ks < 2; ks++) {
            bf16x8 af[MI], bfv[4];
#pragma unroll
            for (int mi = 0; mi < MI; mi++) {
                const int rowA = wr * (MI * 16) + mi * 16 + lr;
                af[mi] = *(const bf16x8*)&Al[cur][rowA * 64 +
                                                  (((ks * 4 + lq) ^ (rowA & 7)) << 3)];
            }
#pragma unroll
            for (int ni = 0; ni < 4; ni++) {
                const int rowB = wc * 64 + ni * 16 + lr;
                bfv[ni] = *(const bf16x8*)&Bl[cur][rowB * 64 +
                                                   (((ks * 4 + lq) ^ (rowB & 7)) << 3)];
            }
#pragma unroll
            for (int mi = 0; mi < MI; mi++)
#pragma unroll
                for (int ni = 0; ni < 4; ni++)
                    acc[mi][ni] = MFMA(af[mi], bfv[ni], acc[mi][ni]);
        }
        asm volatile("s_waitcnt vmcnt(0)" ::: "memory");
        __syncthreads();
        cur ^= 1;
    }
#undef STAGE

#pragma unroll
    for (int mi = 0; mi < MI; mi++)
#pragma unroll
        for (int ni = 0; ni < 4; ni++)
#pragma unroll
            for (int j = 0; j < 4; j++) {
                const int row = m0 + wr * (MI * 16) + mi * 16 + lq * 4 + j;
                const int col = n0 + wc * 64 + ni * 16 + lr;
                const float v = acc[mi][ni][j];
                if (EPI) {
                    ((float*)Cp)[(size_t)row * N + col] =
                        v + bias[col] + resid[(size_t)row * N + col];
                } else if (TRANSC) {
                    ((u16*)Cp)[((size_t)(col >> 11) * 1280 + row) * 2048 +
                               (col & 2047)] = f2bf(v);
                } else {
                    ((u16*)Cp)[(size_t)row * N + col] = f2bf(v);
                }
            }
}

// ---------------------------------------------------------------------------
// Flash attention, barrier-free main loop. Grid 1024 1D:
//   h = id&7 (XCD group), bz = (id>>3)&1, qt = id>>4 (0..63; 16 q-rows each).
// Block 256 thr = 4 waves; wave w: key-half = w&1 (32 of 64 keys),
// parity = w>>1 (tiles kt = 2t+parity). Each wave sweeps its 512 keys with a
// private online softmax (defer-max THR=8); K/V MFMA fragments loaded
// DIRECTLY from global (L1/L2-resident; no LDS staging, no barriers).
// P transposed through tiny wave-private LDS. 4 partials merged at end via
// LDS atomicAdd.
// ---------------------------------------------------------------------------
__global__ __launch_bounds__(256, 4) void attn_kernel(
    const u16* __restrict__ qb, const u16* __restrict__ kb,
    const u16* __restrict__ vtb, const int* __restrict__ seg,
    u16* __restrict__ ao) {
    __shared__ __align__(16) u16 Pl[4][16 * 40];  // per-wave P [16q][32k]+pad
    __shared__ float Osum[16][168];               // merged O (f32)
    __shared__ float Ml[4][16][2];                // per-wave (m,l)
    __shared__ float Lf[16];
    __shared__ u8 segl[4][256];

    const int tid = threadIdx.x;
    const int lane = tid & 63, w = tid >> 6;
    const int lr = lane & 15, lq = lane >> 4;
    const int id = blockIdx.x;
    const int h = id & 7, bz = (id >> 3) & 1, qt = id >> 4;
    const int half = w & 1, par = w >> 1;

    // seg rows qt*4..+4 as bytes
#pragma unroll
    for (int i = 0; i < 4; i++) {
        const int e = i * 256 + tid;
        segl[e >> 8][e & 255] =
            (u8)seg[(size_t)(bz * 256 + qt * 4 + (e >> 8)) * 256 + (e & 255)];
    }
    // zero Osum
    for (int e = tid; e < 16 * 168; e += 256) ((float*)Osum)[e] = 0.f;

    // Q fragments (A-operand): row=lr, k contiguous
    bf16x8 qf[5];
    {
        const size_t grow = (size_t)(bz * 1024 + qt * 16 + lr) * 1280 + h * 160;
#pragma unroll
        for (int ks = 0; ks < 5; ks++)
            qf[ks] = *(const bf16x8*)&qb[grow + ks * 32 + lq * 8];
    }

    float m_i[4] = {0.f, 0.f, 0.f, 0.f}, l_i[4] = {0.f, 0.f, 0.f, 0.f};
    const f32x4 fzero = {0.f, 0.f, 0.f, 0.f};
    f32x4 oacc[10];
#pragma unroll
    for (int d = 0; d < 10; d++) oacc[d] = fzero;

    const float sc = 0.07905694150420949f;  // 1/sqrt(160)
    // K-frag base: key = kt*64 + half*32 + nt*16 + lr ; k = ks*32 + lq*8
    const size_t kfb = ((size_t)(bz * 2048 + half * 32 + lr) * 1280) + h * 160 + lq * 8;
    // V-frag base: d-col = nt2*16+lr, key = kt*64 + half*32 + lq*8
    const size_t vfb = (size_t)(bz * 1280 + h * 160 + lr) * 2048 + half * 32 + lq * 8;
    u16* plw = &Pl[w][0];

    __syncthreads();  // segl + Osum ready

    for (int t = 0; t < 16; t++) {
        const int kt = 2 * t + par;

        // --- K fragments (10 x 16B direct-global) + QK^T ---
        bf16x8 kf[2][5];
#pragma unroll
        for (int nt = 0; nt < 2; nt++)
#pragma unroll
            for (int ks = 0; ks < 5; ks++)
                kf[nt][ks] = *(const bf16x8*)&kb[kfb + (size_t)(kt * 64 + nt * 16) * 1280 +
                                                ks * 32];
        f32x4 s4[2];
#pragma unroll
        for (int nt = 0; nt < 2; nt++) {
            s4[nt] = fzero;
#pragma unroll
            for (int ks = 0; ks < 5; ks++) s4[nt] = MFMA(qf[ks], kf[nt][ks], s4[nt]);
        }

        // --- scale + seg mask (keys >= 1024 iff kt >= 16) ---
        // D layout: row q = lq*4+j, col key = kt*64 + half*32 + nt*16 + lr
#pragma unroll
        for (int nt = 0; nt < 2; nt++) {
            float msk = 0.f;
            if (kt >= 16) {
                const int sg = (kt - 16) * 64 + half * 32 + nt * 16 + lr;
                if (!segl[lq][sg >> 2]) msk = -1e30f;
            }
#pragma unroll
            for (int j = 0; j < 4; j++) s4[nt][j] = s4[nt][j] * sc + msk;
        }

        // --- online softmax over this wave's 32 keys (defer-max THR=8) ---
#pragma unroll
        for (int j = 0; j < 4; j++) {
            float rm = fmaxf(s4[0][j], s4[1][j]);
            rm = fmaxf(rm, __shfl_xor(rm, 1));
            rm = fmaxf(rm, __shfl_xor(rm, 2));
            rm = fmaxf(rm, __shfl_xor(rm, 4));
            rm = fmaxf(rm, __shfl_xor(rm, 8));
            if (__any(rm > m_i[j] + 8.f)) {
                const float mn = fmaxf(m_i[j], rm);
                const float al = __expf(m_i[j] - mn);
                l_i[j] *= al;
                m_i[j] = mn;
#pragma unroll
                for (int d = 0; d < 10; d++) oacc[d][j] *= al;
            }
            float sum = 0.f;
#pragma unroll
            for (int nt = 0; nt < 2; nt++) {
                const float e = __expf(s4[nt][j] - m_i[j]);
                s4[nt][j] = e;
                sum += e;
            }
            sum += __shfl_xor(sum, 1);
            sum += __shfl_xor(sum, 2);
            sum += __shfl_xor(sum, 4);
            sum += __shfl_xor(sum, 8);
            l_i[j] += sum;
        }

        // --- P -> wave-private LDS (u32 packed via lane-pair shfl) ---
#pragma unroll
        for (int nt = 0; nt < 2; nt++)
#pragma unroll
            for (int j = 0; j < 4; j++) {
                const float pv = s4[nt][j];
                const float pp = __shfl_xor(pv, 1);
                if ((lane & 1) == 0) {
                    const u32 pk = (u32)f2bf(pv) | ((u32)f2bf(pp) << 16);
                    *(u32*)&plw[(lq * 4 + j) * 40 + nt * 16 + lr] = pk;
                }
            }

        // --- V fragments (10 x 16B direct-global) + PV ---
        const bf16x8 pa = *(const bf16x8*)&plw[lr * 40 + lq * 8];
#pragma unroll
        for (int nt2 = 0; nt2 < 10; nt2++) {
            const bf16x8 bv =
                *(const bf16x8*)&vtb[vfb + (size_t)(nt2 * 16) * 2048 + kt * 64];
            oacc[nt2] = MFMA(pa, bv, oacc[nt2]);
        }
    }

    // ---- merge the 4 wave partials ----
    if (lr == 0) {
#pragma unroll
        for (int j = 0; j < 4; j++) {
            Ml[w][lq * 4 + j][0] = m_i[j];
            Ml[w][lq * 4 + j][1] = l_i[j];
        }
    }
    __syncthreads();
    float aj[4];
#pragma unroll
    for (int j = 0; j < 4; j++) {
        const int row = lq * 4 + j;
        float M = Ml[0][row][0];
#pragma unroll
        for (int p = 1; p < 4; p++) M = fmaxf(M, Ml[p][row][0]);
        float L = 0.f;
#pragma unroll
        for (int p = 0; p < 4; p++) L += Ml[p][row][1] * __expf(Ml[p][row][0] - M);
        aj[j] = __expf(m_i[j] - M);
        if (w == 0 && lr == 0) Lf[row] = L;
    }
#pragma unroll
    for (int nt2 = 0; nt2 < 10; nt2++)
#pragma unroll
        for (int j = 0; j < 4; j++)
            atomicAdd(&Osum[lq * 4 + j][nt2 * 16 + lr], oacc[nt2][j] * aj[j]);
    __syncthreads();
    if (w == 0) {
#pragma unroll
        for (int nt2 = 0; nt2 < 10; nt2++)
#pragma unroll
            for (int j = 0; j < 4; j++) {
                const int row = lq * 4 + j;
                const float v = Osum[row][nt2 * 16 + lr] / Lf[row];
                const float vp = __shfl_xor(v, 1);
                if ((lane & 1) == 0) {
                    const u32 pk = (u32)f2bf(v) | ((u32)f2bf(vp) << 16);
                    *(u32*)&ao[(size_t)(bz * 1024 + qt * 16 + row) * 1280 + h * 160 +
                               nt2 * 16 + lr] = pk;
                }
            }
    }
}

// ---------------------------------------------------------------------------
extern "C" void kernel_launch(void* const* d_in, const int* in_sizes, int n_in,
                              void* d_out, int out_size, void* d_ws, size_t ws_size,
                              hipStream_t stream) {
    const float* hs  = (const float*)d_in[0];
    const float* ehs = (const float*)d_in[1];
    const int*   seg = (const int*)d_in[2];
    const float* Wq  = (const float*)d_in[3];
    const float* Wk  = (const float*)d_in[4];
    const float* Wv  = (const float*)d_in[5];
    const float* Wo  = (const float*)d_in[6];
    const float* bo  = (const float*)d_in[7];
    float* out = (float*)d_out;

    // ws layout (u16 units). hbuf/aobuf share a region (hbuf dead after
    // Q-GEMM, aobuf written by attn afterwards). Total 55.05 MB.
    u16* base  = (u16*)d_ws;
    u16* WoT   = base;                  // 1,638,400
    u16* qbuf  = WoT + 1638400;         // 2,621,440
    u16* kbuf  = qbuf + 2621440;        // 5,242,880
    u16* vtbuf = kbuf + 5242880;        // 5,242,880
    u16* hbuf  = vtbuf + 5242880;       // 2,621,440 (= aobuf after attn)
    u16* ebuf  = hbuf + 2621440;        // 5,242,880
    u16* WqT   = ebuf + 5242880;        // 1,638,400
    u16* WkT   = WqT + 1638400;         // 1,638,400
    u16* WvT   = WkT + 1638400;         // 1,638,400
    u16* aobuf = hbuf;

    dim3 tb(32, 8), tg(40, 40, 4);
    wtrans_kernel<<<tg, tb, 0, stream>>>(Wq, Wk, Wv, Wo, WqT, WkT, WvT, WoT);
    conv_kernel<<<1280, 256, 0, stream>>>(hs, hbuf, 327680);
    conv_kernel<<<2560, 256, 0, stream>>>(ehs, ebuf, 655360);

    gemm2_kernel<2, false, false><<<dim3(10, 32), 256, 0, stream>>>(
        hbuf, WqT, qbuf, nullptr, nullptr, 2048, 1280, 1280);
    gemm2_kernel<2, false, false><<<dim3(10, 64), 256, 0, stream>>>(
        ebuf, WkT, kbuf, nullptr, nullptr, 4096, 1280, 1280);
    gemm2_kernel<2, true, false><<<dim3(32, 20), 256, 0, stream>>>(
        WvT, ebuf, vtbuf, nullptr, nullptr, 1280, 4096, 1280);

    attn_kernel<<<1024, 256, 0, stream>>>(qbuf, kbuf, vtbuf, seg, aobuf);

    gemm2_kernel<2, false, true><<<dim3(10, 32), 256, 0, stream>>>(
        aobuf, WoT, out, bo, hs, 2048, 1280, 1280);
}